// Round 5
// baseline (381.407 us; speedup 1.0000x reference)
//
#include <hip/hip_runtime.h>
#include <stdint.h>

// ---------------------------------------------------------------------------
// NRI-style graph block:
//   K0: convert weights fp32->bf16 into ws (Wo* also split hi/lo for accuracy)
//   K1 v5: edge MLP per RECEIVER tile: block = (b, n) = that node's 63 in-edges
//          (+1 pad). Computes msgs and reduces them in-block -> agg directly.
//          No msgs buffer, no k2. 48KB LDS -> 3 blocks/CU (R3/R4 lesson: block
//          overlap is the dominant knob). 2-D wave tiles keep LDS traffic low.
//   K3: node MLP in split-bf16 (hi+lo, 3-term MFMA ~ fp32 accuracy) + residual
// ---------------------------------------------------------------------------

typedef __attribute__((ext_vector_type(8))) __bf16 bf16x8;
typedef __attribute__((ext_vector_type(4))) float  f32x4;
typedef __attribute__((ext_vector_type(8))) short  short8;

#define MFMA16(a, b, c) __builtin_amdgcn_mfma_f32_16x16x32_bf16((a), (b), (c), 0, 0, 0)

union U64q { unsigned long long u; __bf16 q[4]; };

static __device__ __forceinline__ unsigned short bfb(__bf16 x) {
  union { __bf16 b; unsigned short u; } c; c.b = x; return c.u;
}

// ---- ws layout (bytes) ----
#define WS_W1    0          // [4][256][128] bf16  (262144 B)
#define WS_W2    262144     // [4][64][256] bf16   (131072 B)
#define WS_O1H   393216     // [256][128] bf16 hi  (65536)
#define WS_O1L   458752
#define WS_O2H   524288     // [256][256] bf16 hi  (131072)
#define WS_O2L   655360
#define WS_O3H   786432     // [64][256] bf16 hi   (32768)
#define WS_O3L   819200
#define WS_AGG   1048576    // [B*N][64] f32       (1048576)
#define WS_NEED  2097152

// ===========================================================================
// K0: weight conversion
// ===========================================================================
__global__ __launch_bounds__(256) void k0_convert(
    const float* __restrict__ W1, const float* __restrict__ W2,
    const float* __restrict__ Wo1, const float* __restrict__ Wo2,
    const float* __restrict__ Wo3, char* __restrict__ ws) {
  int i = blockIdx.x * 256 + threadIdx.x;
  __bf16* w1  = (__bf16*)(ws + WS_W1);
  __bf16* w2  = (__bf16*)(ws + WS_W2);
  __bf16* o1h = (__bf16*)(ws + WS_O1H);
  __bf16* o1l = (__bf16*)(ws + WS_O1L);
  __bf16* o2h = (__bf16*)(ws + WS_O2H);
  __bf16* o2l = (__bf16*)(ws + WS_O2L);
  __bf16* o3h = (__bf16*)(ws + WS_O3H);
  __bf16* o3l = (__bf16*)(ws + WS_O3L);
  if (i < 131072) { w1[i] = (__bf16)W1[i]; return; }
  i -= 131072;
  if (i < 65536) { w2[i] = (__bf16)W2[i]; return; }
  i -= 65536;
  if (i < 32768) { float v = Wo1[i]; __bf16 h = (__bf16)v; o1h[i] = h; o1l[i] = (__bf16)(v - (float)h); return; }
  i -= 32768;
  if (i < 65536) { float v = Wo2[i]; __bf16 h = (__bf16)v; o2h[i] = h; o2l[i] = (__bf16)(v - (float)h); return; }
  i -= 65536;
  if (i < 16384) { float v = Wo3[i]; __bf16 h = (__bf16)v; o3h[i] = h; o3l[i] = (__bf16)(v - (float)h); return; }
}

// ===========================================================================
// K1 v5: one block = receiver (b, n): 63 edges (+1 pad slot), 256 thr, 4 waves.
// G1 (M=256 h1cols, N=64 slots, K=128): wave = 64 cols x 64 slots, acc1[4][4];
//     W1 A-frags from L2, no inter-wave redundancy.
// G2 (M=64 feats, N=64 slots, K=256): 2m x 2n grid, 32x32 tiles, acc2[2][2].
// Epilogue: macc(+b2, relu, *rel_type) summed over slots (shuffle tree + LDS)
//     -> agg[b,n,:] directly.
// LDS: preS [64][256B] swz 16K | h1s [64][512B] swz 32K = 48K -> 3 blocks/CU.
// ===========================================================================
__global__ __launch_bounds__(256, 3) void k1_edge(
    const float* __restrict__ inputs, const float* __restrict__ rel_type,
    const float* __restrict__ b1g, const float* __restrict__ b2g,
    const char* __restrict__ wsr, float* __restrict__ agg) {
  __shared__ char sm[49152];
  char* preS = sm;            // [slot][256B] bf16, byte ^= (slot&7)<<4
  char* h1s  = sm + 16384;    // [slot][512B] bf16, byte ^= (slot&7)<<4
  float* redS = (float*)sm;   // [2][64] f32, reused after kap loop

  const char* w1 = wsr + WS_W1;
  const char* w2 = wsr + WS_W2;

  const int tid = threadIdx.x;
  const int bid = blockIdx.x;
  const int b = bid >> 6, n = bid & 63;
  const int l = tid & 63, w = tid >> 6;
  const int lg = l >> 4, lr = l & 15;

  // ---- stage preS: row j = edge n*63+j; [recv=n feats | send feats] ----
  const float* inpB = inputs + b * 4096;
#pragma unroll
  for (int it = 0; it < 16; ++it) {
    int u = tid + it * 256;        // 0..4095 : 64 rows x 64 float2-units
    int row = u >> 6, up = u & 63;
    int col = up * 2;
    int j = row < 63 ? row : 62;   // pad row dups j=62 (gated by rel_type=0)
    int node = (col < 64) ? n : (j + (j >= n ? 1 : 0));
    int f = col & 63;
    float2 v = *(const float2*)(inpB + node * 64 + f);
    ushort2 p;
    p.x = bfb((__bf16)v.x);
    p.y = bfb((__bf16)v.y);
    int off = (row * 256 + col * 2) ^ ((row & 7) << 4);
    *(ushort2*)(preS + off) = p;
  }
  __syncthreads();

  const int wm = w >> 1, wn = w & 1;   // G2 grid: 2m (feat half) x 2n (slot half)

  // rel_type gates; pad slot (63) gets 0 so it drops out of the reduction
  float reltv[2][4];
#pragma unroll
  for (int nf2 = 0; nf2 < 2; ++nf2) {
    int slot = wn * 32 + nf2 * 16 + lr;
    if (slot < 63) {
      const float* rp = rel_type + ((size_t)b * 4032 + n * 63 + slot) * 4;
#pragma unroll
      for (int kap = 0; kap < 4; ++kap) reltv[nf2][kap] = rp[kap];
    } else {
#pragma unroll
      for (int kap = 0; kap < 4; ++kap) reltv[nf2][kap] = 0.f;
    }
  }

  f32x4 macc[2][2] = {};               // [mf2][nf2] gated msgs accumulator

  for (int kap = 0; kap < 4; ++kap) {
    // ===== G1: acc1[mf][nf], 64 MFMA/wave =====
    f32x4 acc1[4][4] = {};
    const char* w1k = w1 + (size_t)kap * 65536 + (lg << 4);
#pragma unroll
    for (int kq = 0; kq < 4; ++kq) {
      bf16x8 af[4];
#pragma unroll
      for (int mf = 0; mf < 4; ++mf) {
        int colp = w * 64 + mf * 16 + lr;
        af[mf] = *(const bf16x8*)(w1k + colp * 256 + kq * 64);
      }
      bf16x8 bfr[4];
#pragma unroll
      for (int nf = 0; nf < 4; ++nf) {
        int slot = nf * 16 + lr;
        int off = (slot * 256 + kq * 64 + (lg << 4)) ^ ((lr & 7) << 4);
        bfr[nf] = *(const bf16x8*)(preS + off);
      }
#pragma unroll
      for (int mf = 0; mf < 4; ++mf)
#pragma unroll
        for (int nf = 0; nf < 4; ++nf)
          acc1[mf][nf] = MFMA16(af[mf], bfr[nf], acc1[mf][nf]);
    }

    __syncthreads();   // barrier A: previous kap's G2 done reading h1s

    // h1 epilogue: +b1, relu, bf16, b64 write (4 consecutive cols per lane)
#pragma unroll
    for (int mf = 0; mf < 4; ++mf) {
      int col0 = w * 64 + mf * 16 + (lg << 2);
      f32x4 bv = *(const f32x4*)(b1g + kap * 256 + col0);
#pragma unroll
      for (int nf = 0; nf < 4; ++nf) {
        int slot = nf * 16 + lr;
        U64q pk;
#pragma unroll
        for (int i2 = 0; i2 < 4; ++i2)
          pk.q[i2] = (__bf16)fmaxf(acc1[mf][nf][i2] + bv[i2], 0.f);
        int off = (slot * 512 + col0 * 2) ^ ((lr & 7) << 4);
        *(unsigned long long*)(h1s + off) = pk.u;
      }
    }
    __syncthreads();   // barrier B: h1 ready

    // ===== G2: acc2[mf2][nf2], 32 MFMA/wave =====
    f32x4 acc2[2][2] = {};
    const char* w2k = w2 + (size_t)kap * 32768 + (lg << 4);
#pragma unroll
    for (int kk = 0; kk < 8; ++kk) {
      bf16x8 a2[2];
#pragma unroll
      for (int mf2 = 0; mf2 < 2; ++mf2) {
        int feat = wm * 32 + mf2 * 16 + lr;
        a2[mf2] = *(const bf16x8*)(w2k + feat * 512 + kk * 64);
      }
      bf16x8 b2f[2];
#pragma unroll
      for (int nf2 = 0; nf2 < 2; ++nf2) {
        int slot = wn * 32 + nf2 * 16 + lr;
        int off = (slot * 512 + kk * 64 + (lg << 4)) ^ ((lr & 7) << 4);
        b2f[nf2] = *(const bf16x8*)(h1s + off);
      }
#pragma unroll
      for (int mf2 = 0; mf2 < 2; ++mf2)
#pragma unroll
        for (int nf2 = 0; nf2 < 2; ++nf2)
          acc2[mf2][nf2] = MFMA16(a2[mf2], b2f[nf2], acc2[mf2][nf2]);
    }

    // ---- macc += relu(acc2 + b2) * rel_type[kap] ----
#pragma unroll
    for (int mf2 = 0; mf2 < 2; ++mf2) {
      int col0 = wm * 32 + mf2 * 16 + (lg << 2);
      f32x4 bv = *(const f32x4*)(b2g + kap * 64 + col0);
#pragma unroll
      for (int nf2 = 0; nf2 < 2; ++nf2) {
        float rt = reltv[nf2][kap];
#pragma unroll
        for (int i2 = 0; i2 < 4; ++i2)
          macc[mf2][nf2][i2] += fmaxf(acc2[mf2][nf2][i2] + bv[i2], 0.f) * rt;
      }
    }
  }

  // ---- reduce msgs over slots -> agg[b,n,:] ----
  // lane (lg,lr) of wave (wm,wn): macc[mf2][nf2][i2] is msg for
  //   feature = wm*32 + mf2*16 + lg*4 + i2, slot = wn*32 + nf2*16 + lr.
  float s[2][4];
#pragma unroll
  for (int mf2 = 0; mf2 < 2; ++mf2)
#pragma unroll
    for (int i2 = 0; i2 < 4; ++i2)
      s[mf2][i2] = macc[mf2][0][i2] + macc[mf2][1][i2];
#pragma unroll
  for (int mask = 1; mask < 16; mask <<= 1)
#pragma unroll
    for (int mf2 = 0; mf2 < 2; ++mf2)
#pragma unroll
      for (int i2 = 0; i2 < 4; ++i2)
        s[mf2][i2] += __shfl_xor(s[mf2][i2], mask);

  __syncthreads();   // everyone done with preS region before redS reuse
  if (lr == 0) {
#pragma unroll
    for (int mf2 = 0; mf2 < 2; ++mf2) {
      f32x4 v; v[0] = s[mf2][0]; v[1] = s[mf2][1]; v[2] = s[mf2][2]; v[3] = s[mf2][3];
      *(f32x4*)(redS + wn * 64 + wm * 32 + mf2 * 16 + (lg << 2)) = v;
    }
  }
  __syncthreads();
  if (tid < 64)
    agg[((size_t)b * 64 + n) * 64 + tid] = redS[tid] + redS[64 + tid];
}

// ===========================================================================
// K3: node MLP with split-bf16 (hi+lo) 3-term MFMA (~fp32 accuracy) + residual
// One block = 32 node-rows. 256 threads (4 waves).
// ===========================================================================
__global__ __launch_bounds__(256) void k3_node(
    const float* __restrict__ inputs, const float* __restrict__ agg,
    const char* __restrict__ wsr,
    const float* __restrict__ bo1, const float* __restrict__ bo2,
    const float* __restrict__ bo3, float* __restrict__ out) {
  __shared__ char sm[65536];
  char* augHi = sm;                  // [32][128] bf16 swz
  char* augLo = sm + 8192;
  char* h1hi  = sm + 16384;          // [32][256] bf16 swz
  char* h1lo  = sm + 32768;
  char* h2hi  = sm;                  // reuse aug region after GEMM1
  char* h2lo  = sm + 49152;

  const char* o1h = wsr + WS_O1H;
  const char* o1l = wsr + WS_O1L;
  const char* o2h = wsr + WS_O2H;
  const char* o2l = wsr + WS_O2L;
  const char* o3h = wsr + WS_O3H;
  const char* o3l = wsr + WS_O3L;

  const int tid = threadIdx.x;
  const int l = tid & 63;
  const int w = tid >> 6;
  const int lg = l >> 4, lr = l & 15;
  const int r0 = blockIdx.x * 32;

  // ---- stage aug = [inputs | agg] as hi/lo bf16 ----
  for (int it = 0; it < 8; ++it) {
    int u = tid + it * 256;          // 0..2047 ; 32 rows x 64 (2-col units)
    int row = u >> 6, up = u & 63;
    int col = up * 2;
    const float* src = (col < 64) ? (inputs + (r0 + row) * 64 + col)
                                  : (agg + (r0 + row) * 64 + (col - 64));
    float2 v = *(const float2*)src;
    __bf16 h0 = (__bf16)v.x, h1v = (__bf16)v.y;
    __bf16 l0 = (__bf16)(v.x - (float)h0), l1 = (__bf16)(v.y - (float)h1v);
    int off = (row * 256 + col * 2) ^ ((row & 7) << 4);
    ushort2 ph; ph.x = bfb(h0); ph.y = bfb(h1v);
    ushort2 pl; pl.x = bfb(l0); pl.y = bfb(l1);
    *(ushort2*)(augHi + off) = ph;
    *(ushort2*)(augLo + off) = pl;
  }
  __syncthreads();

  // ===== GEMM1: h1^T = Wo1 @ aug^T (M=256, N=32, K=128), 3-term split =====
  f32x4 acc[4][2] = {};
#pragma unroll
  for (int kk = 0; kk < 4; ++kk) {
    bf16x8 ah[4], al[4], bh[2], bl[2];
#pragma unroll
    for (int mfi = 0; mfi < 4; ++mfi) {
      int colp = w * 64 + mfi * 16 + lr;
      int gb = colp * 256 + kk * 64 + (lg << 4);
      ah[mfi] = *(const bf16x8*)(o1h + gb);
      al[mfi] = *(const bf16x8*)(o1l + gb);
    }
#pragma unroll
    for (int nfi = 0; nfi < 2; ++nfi) {
      int row = nfi * 16 + lr;
      int off = (row * 256 + kk * 64 + (lg << 4)) ^ ((row & 7) << 4);
      bh[nfi] = *(const bf16x8*)(augHi + off);
      bl[nfi] = *(const bf16x8*)(augLo + off);
    }
#pragma unroll
    for (int mfi = 0; mfi < 4; ++mfi)
#pragma unroll
      for (int nfi = 0; nfi < 2; ++nfi) {
        acc[mfi][nfi] = MFMA16(ah[mfi], bh[nfi], acc[mfi][nfi]);
        acc[mfi][nfi] = MFMA16(ah[mfi], bl[nfi], acc[mfi][nfi]);
        acc[mfi][nfi] = MFMA16(al[mfi], bh[nfi], acc[mfi][nfi]);
      }
  }
#pragma unroll
  for (int mfi = 0; mfi < 4; ++mfi) {
    int col0 = w * 64 + mfi * 16 + (lg << 2);
    f32x4 bv = *(const f32x4*)(bo1 + col0);
#pragma unroll
    for (int nfi = 0; nfi < 2; ++nfi) {
      int row = nfi * 16 + lr;
      U64q ph, pl;
#pragma unroll
      for (int i2 = 0; i2 < 4; ++i2) {
        float x = fmaxf(acc[mfi][nfi][i2] + bv[i2], 0.f);
        ph.q[i2] = (__bf16)x;
        pl.q[i2] = (__bf16)(x - (float)ph.q[i2]);
      }
      int off = (row * 512 + col0 * 2) ^ ((row & 7) << 4);
      *(unsigned long long*)(h1hi + off) = ph.u;
      *(unsigned long long*)(h1lo + off) = pl.u;
    }
  }
  __syncthreads();

  // ===== GEMM2: h2^T = Wo2 @ h1^T (M=256, N=32, K=256) =====
  f32x4 acc2[4][2] = {};
#pragma unroll
  for (int kk = 0; kk < 8; ++kk) {
    bf16x8 ah[4], al[4], bh[2], bl[2];
#pragma unroll
    for (int mfi = 0; mfi < 4; ++mfi) {
      int colp = w * 64 + mfi * 16 + lr;
      int gb = colp * 512 + kk * 64 + (lg << 4);
      ah[mfi] = *(const bf16x8*)(o2h + gb);
      al[mfi] = *(const bf16x8*)(o2l + gb);
    }
#pragma unroll
    for (int nfi = 0; nfi < 2; ++nfi) {
      int row = nfi * 16 + lr;
      int off = (row * 512 + kk * 64 + (lg << 4)) ^ ((row & 7) << 4);
      bh[nfi] = *(const bf16x8*)(h1hi + off);
      bl[nfi] = *(const bf16x8*)(h1lo + off);
    }
#pragma unroll
    for (int mfi = 0; mfi < 4; ++mfi)
#pragma unroll
      for (int nfi = 0; nfi < 2; ++nfi) {
        acc2[mfi][nfi] = MFMA16(ah[mfi], bh[nfi], acc2[mfi][nfi]);
        acc2[mfi][nfi] = MFMA16(ah[mfi], bl[nfi], acc2[mfi][nfi]);
        acc2[mfi][nfi] = MFMA16(al[mfi], bh[nfi], acc2[mfi][nfi]);
      }
  }
#pragma unroll
  for (int mfi = 0; mfi < 4; ++mfi) {
    int col0 = w * 64 + mfi * 16 + (lg << 2);
    f32x4 bv = *(const f32x4*)(bo2 + col0);
#pragma unroll
    for (int nfi = 0; nfi < 2; ++nfi) {
      int row = nfi * 16 + lr;
      U64q ph, pl;
#pragma unroll
      for (int i2 = 0; i2 < 4; ++i2) {
        float x = fmaxf(acc2[mfi][nfi][i2] + bv[i2], 0.f);
        ph.q[i2] = (__bf16)x;
        pl.q[i2] = (__bf16)(x - (float)ph.q[i2]);
      }
      int off = (row * 512 + col0 * 2) ^ ((row & 7) << 4);
      *(unsigned long long*)(h2hi + off) = ph.u;
      *(unsigned long long*)(h2lo + off) = pl.u;
    }
  }
  __syncthreads();

  // ===== GEMM3: pred^T = Wo3 @ h2^T (M=64, N=32, K=256) + residual =====
  f32x4 acc3[2] = {};
#pragma unroll
  for (int kk = 0; kk < 8; ++kk) {
    int colp = w * 16 + lr;
    int gb = colp * 512 + kk * 64 + (lg << 4);
    bf16x8 a3h = *(const bf16x8*)(o3h + gb);
    bf16x8 a3l = *(const bf16x8*)(o3l + gb);
#pragma unroll
    for (int nfi = 0; nfi < 2; ++nfi) {
      int row = nfi * 16 + lr;
      int off = (row * 512 + kk * 64 + (lg << 4)) ^ ((row & 7) << 4);
      bf16x8 b3h = *(const bf16x8*)(h2hi + off);
      bf16x8 b3l = *(const bf16x8*)(h2lo + off);
      acc3[nfi] = MFMA16(a3h, b3h, acc3[nfi]);
      acc3[nfi] = MFMA16(a3h, b3l, acc3[nfi]);
      acc3[nfi] = MFMA16(a3l, b3h, acc3[nfi]);
    }
  }
#pragma unroll
  for (int nfi = 0; nfi < 2; ++nfi) {
    int row = nfi * 16 + lr;
    int col0 = w * 16 + (lg << 2);
    f32x4 bv = *(const f32x4*)(bo3 + col0);
    f32x4 iv = *(const f32x4*)(inputs + (r0 + row) * 64 + col0);
    f32x4 o;
#pragma unroll
    for (int i2 = 0; i2 < 4; ++i2) o[i2] = acc3[nfi][i2] + bv[i2] + iv[i2];
    *(f32x4*)(out + (r0 + row) * 64 + col0) = o;
  }
}

// ===========================================================================
extern "C" void kernel_launch(void* const* d_in, const int* in_sizes, int n_in,
                              void* d_out, int out_size, void* d_ws, size_t ws_size,
                              hipStream_t stream) {
  (void)in_sizes; (void)n_in; (void)out_size;
  if (ws_size < (size_t)WS_NEED) return;  // need 2 MB scratch

  const float* inputs   = (const float*)d_in[0];
  const float* rel_type = (const float*)d_in[1];
  const float* W1  = (const float*)d_in[4];
  const float* b1  = (const float*)d_in[5];
  const float* W2  = (const float*)d_in[6];
  const float* b2  = (const float*)d_in[7];
  const float* Wo1 = (const float*)d_in[8];
  const float* bo1 = (const float*)d_in[9];
  const float* Wo2 = (const float*)d_in[10];
  const float* bo2 = (const float*)d_in[11];
  const float* Wo3 = (const float*)d_in[12];
  const float* bo3 = (const float*)d_in[13];

  char* ws = (char*)d_ws;
  float* agg  = (float*)(ws + WS_AGG);
  float* out  = (float*)d_out;

  k0_convert<<<dim3(1216), dim3(256), 0, stream>>>(W1, W2, Wo1, Wo2, Wo3, ws);
  k1_edge<<<dim3(4096), dim3(256), 0, stream>>>(inputs, rel_type, b1, b2, ws, agg);
  k3_node<<<dim3(128), dim3(256), 0, stream>>>(inputs, agg, ws, bo1, bo2, bo3, out);
}

// Round 6
// 349.335 us; speedup vs baseline: 1.0918x; 1.0918x over previous
//
#include <hip/hip_runtime.h>
#include <stdint.h>

// ---------------------------------------------------------------------------
// NRI-style graph block:
//   K0: convert weights fp32->bf16 into ws (Wo* also split hi/lo for accuracy)
//   K1 v6: receiver-tiled edge MLP. block = (b,n) = 63 in-edges (+1 pad).
//     Rank-1 split: h1 = relu(W1send@send + (W1recv@x_n + b1)) -- recv part
//     computed once per block (f32 VALU), so GEMM1 K halves to 64.
//     In-block gated sum -> agg directly (no msgs HBM, no k2).
//     __launch_bounds__(256) ONLY: empirically cap = 256/arg2
//     ((512,4)->64, (256,3)->85, (512,2)->128) -- arg2>=3 caused spills.
//   K3: node MLP in split-bf16 (hi+lo, 3-term MFMA ~ fp32 accuracy) + residual
// ---------------------------------------------------------------------------

typedef __attribute__((ext_vector_type(8))) __bf16 bf16x8;
typedef __attribute__((ext_vector_type(4))) float  f32x4;
typedef __attribute__((ext_vector_type(8))) short  short8;

#define MFMA16(a, b, c) __builtin_amdgcn_mfma_f32_16x16x32_bf16((a), (b), (c), 0, 0, 0)

union U64q { unsigned long long u; __bf16 q[4]; };

static __device__ __forceinline__ unsigned short bfb(__bf16 x) {
  union { __bf16 b; unsigned short u; } c; c.b = x; return c.u;
}

// ---- ws layout (bytes) ----
#define WS_W1    0          // [4][256][128] bf16  (262144 B)
#define WS_W2    262144     // [4][64][256] bf16   (131072 B)
#define WS_O1H   393216     // [256][128] bf16 hi  (65536)
#define WS_O1L   458752
#define WS_O2H   524288     // [256][256] bf16 hi  (131072)
#define WS_O2L   655360
#define WS_O3H   786432     // [64][256] bf16 hi   (32768)
#define WS_O3L   819200
#define WS_AGG   1048576    // [B*N][64] f32       (1048576)
#define WS_NEED  2097152

// k1 LDS layout (bytes)
#define L_PRE 0        // [64 slots][128B] bf16 send feats, ^((slot&7)<<4)
#define L_H1  8192     // [64 slots][512B] bf16 h1, ^((slot&7)<<4)
#define L_HR  40960    // [4 kap][256] f32 : W1recv@x_n + b1
#define L_XN  45056    // [64] f32 receiver features
#define L_SZ  45312

// ===========================================================================
// K0: weight conversion
// ===========================================================================
__global__ __launch_bounds__(256) void k0_convert(
    const float* __restrict__ W1, const float* __restrict__ W2,
    const float* __restrict__ Wo1, const float* __restrict__ Wo2,
    const float* __restrict__ Wo3, char* __restrict__ ws) {
  int i = blockIdx.x * 256 + threadIdx.x;
  __bf16* w1  = (__bf16*)(ws + WS_W1);
  __bf16* w2  = (__bf16*)(ws + WS_W2);
  __bf16* o1h = (__bf16*)(ws + WS_O1H);
  __bf16* o1l = (__bf16*)(ws + WS_O1L);
  __bf16* o2h = (__bf16*)(ws + WS_O2H);
  __bf16* o2l = (__bf16*)(ws + WS_O2L);
  __bf16* o3h = (__bf16*)(ws + WS_O3H);
  __bf16* o3l = (__bf16*)(ws + WS_O3L);
  if (i < 131072) { w1[i] = (__bf16)W1[i]; return; }
  i -= 131072;
  if (i < 65536) { w2[i] = (__bf16)W2[i]; return; }
  i -= 65536;
  if (i < 32768) { float v = Wo1[i]; __bf16 h = (__bf16)v; o1h[i] = h; o1l[i] = (__bf16)(v - (float)h); return; }
  i -= 32768;
  if (i < 65536) { float v = Wo2[i]; __bf16 h = (__bf16)v; o2h[i] = h; o2l[i] = (__bf16)(v - (float)h); return; }
  i -= 65536;
  if (i < 16384) { float v = Wo3[i]; __bf16 h = (__bf16)v; o3h[i] = h; o3l[i] = (__bf16)(v - (float)h); return; }
}

// ===========================================================================
// K1 v6: one block = receiver (b,n), 256 thr (4 waves), 63 edges + 1 pad slot.
// G1 (M=256 h1cols, N=64 slots, K=64 send feats): wave tile 64x64, acc1[4][4].
// G2 (M=64 feats, N=64 slots, K=256): 2m x 2n grid, 32x32 tiles, acc2[2][2].
// Reduce gated msgs over slots (shuffle + LDS) -> agg[b,n,:].
// ===========================================================================
__global__ __launch_bounds__(256) void k1_edge(
    const float* __restrict__ inputs, const float* __restrict__ rel_type,
    const float* __restrict__ b1g, const float* __restrict__ b2g,
    const char* __restrict__ wsr, float* __restrict__ agg) {
  __shared__ char sm[L_SZ];
  char*  preS = sm + L_PRE;
  char*  h1s  = sm + L_H1;
  float* hr   = (float*)(sm + L_HR);
  float* xn   = (float*)(sm + L_XN);
  float* redS = (float*)sm;          // reuses preS region after last G1

  const int tid = threadIdx.x;
  const int bid = blockIdx.x;
  const int b = bid >> 6, n = bid & 63;
  const int l = tid & 63, w = tid >> 6;
  const int lg = l >> 4, lr = l & 15;

  const float* inpB = inputs + b * 4096;

  // ---- stage xn (receiver feats, f32) and preS (send feats, bf16) ----
  if (tid < 64) xn[tid] = inpB[n * 64 + tid];
#pragma unroll
  for (int it = 0; it < 8; ++it) {
    int u = tid + it * 256;          // 0..2047 : 64 slots x 32 float2-units
    int row = u >> 5, up = u & 31;
    int j = row < 63 ? row : 62;     // pad slot dups j=62 (rel_type gate = 0)
    int s = j + (j >= n ? 1 : 0);
    float2 v = *(const float2*)(inpB + s * 64 + up * 2);
    ushort2 p;
    p.x = bfb((__bf16)v.x);
    p.y = bfb((__bf16)v.y);
    int off = (row * 128 + up * 4) ^ ((row & 7) << 4);
    *(ushort2*)(preS + off) = p;
  }
  __syncthreads();

  // ---- h1recv[kap][col] = W1recv[kap][col][:] @ xn + b1[kap][col] ----
  {
    const __bf16* w1b = (const __bf16*)(wsr + WS_W1);
#pragma unroll
    for (int kap = 0; kap < 4; ++kap) {
      const __bf16* wrow = w1b + kap * 32768 + tid * 128;   // recv = feats 0..63
      float acc = b1g[kap * 256 + tid];
#pragma unroll
      for (int c = 0; c < 8; ++c) {
        bf16x8 wv = *(const bf16x8*)(wrow + c * 8);
#pragma unroll
        for (int e = 0; e < 8; ++e) acc += (float)wv[e] * xn[c * 8 + e];
      }
      hr[kap * 256 + tid] = acc;
    }
  }

  const int wm = w >> 1, wn = w & 1;   // G2 grid: 2m (feat half) x 2n (slot half)

  // rel_type gates; pad slot 63 -> 0
  float reltv[2][4];
#pragma unroll
  for (int nf2 = 0; nf2 < 2; ++nf2) {
    int slot = wn * 32 + nf2 * 16 + lr;
    if (slot < 63) {
      const float* rp = rel_type + ((size_t)b * 4032 + n * 63 + slot) * 4;
#pragma unroll
      for (int kap = 0; kap < 4; ++kap) reltv[nf2][kap] = rp[kap];
    } else {
#pragma unroll
      for (int kap = 0; kap < 4; ++kap) reltv[nf2][kap] = 0.f;
    }
  }
  __syncthreads();    // hr ready (and preS, staged above)

  f32x4 macc[2][2] = {};               // [mf2][nf2] gated msgs accumulator

  for (int kap = 0; kap < 4; ++kap) {
    // ===== G1: h1send^T = W1send @ send^T (K=64), 32 MFMA/wave =====
    f32x4 acc1[4][4] = {};
    const char* w1k = wsr + WS_W1 + kap * 65536 + 128 + (lg << 4);  // +128B: send half
    bf16x8 af[2][4];
#pragma unroll
    for (int kq = 0; kq < 2; ++kq)
#pragma unroll
      for (int mf = 0; mf < 4; ++mf) {
        int colp = w * 64 + mf * 16 + lr;
        af[kq][mf] = *(const bf16x8*)(w1k + colp * 256 + kq * 64);
      }
#pragma unroll
    for (int kq = 0; kq < 2; ++kq) {
      bf16x8 bfr[4];
#pragma unroll
      for (int nf = 0; nf < 4; ++nf) {
        int slot = nf * 16 + lr;
        int off = (slot * 128 + kq * 64 + (lg << 4)) ^ ((lr & 7) << 4);
        bfr[nf] = *(const bf16x8*)(preS + off);
      }
#pragma unroll
      for (int mf = 0; mf < 4; ++mf)
#pragma unroll
        for (int nf = 0; nf < 4; ++nf)
          acc1[mf][nf] = MFMA16(af[kq][mf], bfr[nf], acc1[mf][nf]);
    }

    __syncthreads();   // barrier A: previous kap's G2 done reading h1s

    // h1 epilogue: + (recv dot + b1), relu, bf16, b64 write
#pragma unroll
    for (int mf = 0; mf < 4; ++mf) {
      int col0 = w * 64 + mf * 16 + (lg << 2);
      f32x4 rv = *(const f32x4*)(hr + kap * 256 + col0);
#pragma unroll
      for (int nf = 0; nf < 4; ++nf) {
        int slot = nf * 16 + lr;
        U64q pk;
#pragma unroll
        for (int i2 = 0; i2 < 4; ++i2)
          pk.q[i2] = (__bf16)fmaxf(acc1[mf][nf][i2] + rv[i2], 0.f);
        int off = (slot * 512 + col0 * 2) ^ ((lr & 7) << 4);
        *(unsigned long long*)(h1s + off) = pk.u;
      }
    }
    __syncthreads();   // barrier B: h1 ready

    // ===== G2: h2^T = W2 @ h1^T (K=256), 32 MFMA/wave =====
    f32x4 acc2[2][2] = {};
    const char* w2k = wsr + WS_W2 + kap * 32768 + (lg << 4);
#pragma unroll
    for (int kk = 0; kk < 8; ++kk) {
      bf16x8 a2[2];
#pragma unroll
      for (int mf2 = 0; mf2 < 2; ++mf2) {
        int feat = wm * 32 + mf2 * 16 + lr;
        a2[mf2] = *(const bf16x8*)(w2k + feat * 512 + kk * 64);
      }
      bf16x8 b2f[2];
#pragma unroll
      for (int nf2 = 0; nf2 < 2; ++nf2) {
        int slot = wn * 32 + nf2 * 16 + lr;
        int off = (slot * 512 + kk * 64 + (lg << 4)) ^ ((lr & 7) << 4);
        b2f[nf2] = *(const bf16x8*)(h1s + off);
      }
#pragma unroll
      for (int mf2 = 0; mf2 < 2; ++mf2)
#pragma unroll
        for (int nf2 = 0; nf2 < 2; ++nf2)
          acc2[mf2][nf2] = MFMA16(a2[mf2], b2f[nf2], acc2[mf2][nf2]);
    }

    // ---- macc += relu(acc2 + b2) * rel_type[kap] ----
#pragma unroll
    for (int mf2 = 0; mf2 < 2; ++mf2) {
      int col0 = wm * 32 + mf2 * 16 + (lg << 2);
      f32x4 bv = *(const f32x4*)(b2g + kap * 64 + col0);
#pragma unroll
      for (int nf2 = 0; nf2 < 2; ++nf2) {
        float rt = reltv[nf2][kap];
#pragma unroll
        for (int i2 = 0; i2 < 4; ++i2)
          macc[mf2][nf2][i2] += fmaxf(acc2[mf2][nf2][i2] + bv[i2], 0.f) * rt;
      }
    }
  }

  // ---- reduce gated msgs over slots -> agg[b,n,:] ----
  float s[2][4];
#pragma unroll
  for (int mf2 = 0; mf2 < 2; ++mf2)
#pragma unroll
    for (int i2 = 0; i2 < 4; ++i2)
      s[mf2][i2] = macc[mf2][0][i2] + macc[mf2][1][i2];
#pragma unroll
  for (int mask = 1; mask < 16; mask <<= 1)
#pragma unroll
    for (int mf2 = 0; mf2 < 2; ++mf2)
#pragma unroll
      for (int i2 = 0; i2 < 4; ++i2)
        s[mf2][i2] += __shfl_xor(s[mf2][i2], mask);

  __syncthreads();   // all waves past last preS/h1s use before redS reuse
  if (lr == 0) {
#pragma unroll
    for (int mf2 = 0; mf2 < 2; ++mf2) {
      f32x4 v; v[0] = s[mf2][0]; v[1] = s[mf2][1]; v[2] = s[mf2][2]; v[3] = s[mf2][3];
      *(f32x4*)(redS + wn * 64 + wm * 32 + mf2 * 16 + (lg << 2)) = v;
    }
  }
  __syncthreads();
  if (tid < 64)
    agg[((size_t)b * 64 + n) * 64 + tid] = redS[tid] + redS[64 + tid];
}

// ===========================================================================
// K3: node MLP with split-bf16 (hi+lo) 3-term MFMA (~fp32 accuracy) + residual
// One block = 32 node-rows. 256 threads (4 waves).
// ===========================================================================
__global__ __launch_bounds__(256) void k3_node(
    const float* __restrict__ inputs, const float* __restrict__ agg,
    const char* __restrict__ wsr,
    const float* __restrict__ bo1, const float* __restrict__ bo2,
    const float* __restrict__ bo3, float* __restrict__ out) {
  __shared__ char sm[65536];
  char* augHi = sm;                  // [32][128] bf16 swz
  char* augLo = sm + 8192;
  char* h1hi  = sm + 16384;          // [32][256] bf16 swz
  char* h1lo  = sm + 32768;
  char* h2hi  = sm;                  // reuse aug region after GEMM1
  char* h2lo  = sm + 49152;

  const char* o1h = wsr + WS_O1H;
  const char* o1l = wsr + WS_O1L;
  const char* o2h = wsr + WS_O2H;
  const char* o2l = wsr + WS_O2L;
  const char* o3h = wsr + WS_O3H;
  const char* o3l = wsr + WS_O3L;

  const int tid = threadIdx.x;
  const int l = tid & 63;
  const int w = tid >> 6;
  const int lg = l >> 4, lr = l & 15;
  const int r0 = blockIdx.x * 32;

  // ---- stage aug = [inputs | agg] as hi/lo bf16 ----
  for (int it = 0; it < 8; ++it) {
    int u = tid + it * 256;          // 0..2047 ; 32 rows x 64 (2-col units)
    int row = u >> 6, up = u & 63;
    int col = up * 2;
    const float* src = (col < 64) ? (inputs + (r0 + row) * 64 + col)
                                  : (agg + (r0 + row) * 64 + (col - 64));
    float2 v = *(const float2*)src;
    __bf16 h0 = (__bf16)v.x, h1v = (__bf16)v.y;
    __bf16 l0 = (__bf16)(v.x - (float)h0), l1 = (__bf16)(v.y - (float)h1v);
    int off = (row * 256 + col * 2) ^ ((row & 7) << 4);
    ushort2 ph; ph.x = bfb(h0); ph.y = bfb(h1v);
    ushort2 pl; pl.x = bfb(l0); pl.y = bfb(l1);
    *(ushort2*)(augHi + off) = ph;
    *(ushort2*)(augLo + off) = pl;
  }
  __syncthreads();

  // ===== GEMM1: h1^T = Wo1 @ aug^T (M=256, N=32, K=128), 3-term split =====
  f32x4 acc[4][2] = {};
#pragma unroll
  for (int kk = 0; kk < 4; ++kk) {
    bf16x8 ah[4], al[4], bh[2], bl[2];
#pragma unroll
    for (int mfi = 0; mfi < 4; ++mfi) {
      int colp = w * 64 + mfi * 16 + lr;
      int gb = colp * 256 + kk * 64 + (lg << 4);
      ah[mfi] = *(const bf16x8*)(o1h + gb);
      al[mfi] = *(const bf16x8*)(o1l + gb);
    }
#pragma unroll
    for (int nfi = 0; nfi < 2; ++nfi) {
      int row = nfi * 16 + lr;
      int off = (row * 256 + kk * 64 + (lg << 4)) ^ ((row & 7) << 4);
      bh[nfi] = *(const bf16x8*)(augHi + off);
      bl[nfi] = *(const bf16x8*)(augLo + off);
    }
#pragma unroll
    for (int mfi = 0; mfi < 4; ++mfi)
#pragma unroll
      for (int nfi = 0; nfi < 2; ++nfi) {
        acc[mfi][nfi] = MFMA16(ah[mfi], bh[nfi], acc[mfi][nfi]);
        acc[mfi][nfi] = MFMA16(ah[mfi], bl[nfi], acc[mfi][nfi]);
        acc[mfi][nfi] = MFMA16(al[mfi], bh[nfi], acc[mfi][nfi]);
      }
  }
#pragma unroll
  for (int mfi = 0; mfi < 4; ++mfi) {
    int col0 = w * 64 + mfi * 16 + (lg << 2);
    f32x4 bv = *(const f32x4*)(bo1 + col0);
#pragma unroll
    for (int nfi = 0; nfi < 2; ++nfi) {
      int row = nfi * 16 + lr;
      U64q ph, pl;
#pragma unroll
      for (int i2 = 0; i2 < 4; ++i2) {
        float x = fmaxf(acc[mfi][nfi][i2] + bv[i2], 0.f);
        ph.q[i2] = (__bf16)x;
        pl.q[i2] = (__bf16)(x - (float)ph.q[i2]);
      }
      int off = (row * 512 + col0 * 2) ^ ((row & 7) << 4);
      *(unsigned long long*)(h1hi + off) = ph.u;
      *(unsigned long long*)(h1lo + off) = pl.u;
    }
  }
  __syncthreads();

  // ===== GEMM2: h2^T = Wo2 @ h1^T (M=256, N=32, K=256) =====
  f32x4 acc2[4][2] = {};
#pragma unroll
  for (int kk = 0; kk < 8; ++kk) {
    bf16x8 ah[4], al[4], bh[2], bl[2];
#pragma unroll
    for (int mfi = 0; mfi < 4; ++mfi) {
      int colp = w * 64 + mfi * 16 + lr;
      int gb = colp * 512 + kk * 64 + (lg << 4);
      ah[mfi] = *(const bf16x8*)(o2h + gb);
      al[mfi] = *(const bf16x8*)(o2l + gb);
    }
#pragma unroll
    for (int nfi = 0; nfi < 2; ++nfi) {
      int row = nfi * 16 + lr;
      int off = (row * 512 + kk * 64 + (lg << 4)) ^ ((row & 7) << 4);
      bh[nfi] = *(const bf16x8*)(h1hi + off);
      bl[nfi] = *(const bf16x8*)(h1lo + off);
    }
#pragma unroll
    for (int mfi = 0; mfi < 4; ++mfi)
#pragma unroll
      for (int nfi = 0; nfi < 2; ++nfi) {
        acc2[mfi][nfi] = MFMA16(ah[mfi], bh[nfi], acc2[mfi][nfi]);
        acc2[mfi][nfi] = MFMA16(ah[mfi], bl[nfi], acc2[mfi][nfi]);
        acc2[mfi][nfi] = MFMA16(al[mfi], bh[nfi], acc2[mfi][nfi]);
      }
  }
#pragma unroll
  for (int mfi = 0; mfi < 4; ++mfi) {
    int col0 = w * 64 + mfi * 16 + (lg << 2);
    f32x4 bv = *(const f32x4*)(bo2 + col0);
#pragma unroll
    for (int nfi = 0; nfi < 2; ++nfi) {
      int row = nfi * 16 + lr;
      U64q ph, pl;
#pragma unroll
      for (int i2 = 0; i2 < 4; ++i2) {
        float x = fmaxf(acc2[mfi][nfi][i2] + bv[i2], 0.f);
        ph.q[i2] = (__bf16)x;
        pl.q[i2] = (__bf16)(x - (float)ph.q[i2]);
      }
      int off = (row * 512 + col0 * 2) ^ ((row & 7) << 4);
      *(unsigned long long*)(h2hi + off) = ph.u;
      *(unsigned long long*)(h2lo + off) = pl.u;
    }
  }
  __syncthreads();

  // ===== GEMM3: pred^T = Wo3 @ h2^T (M=64, N=32, K=256) + residual =====
  f32x4 acc3[2] = {};
#pragma unroll
  for (int kk = 0; kk < 8; ++kk) {
    int colp = w * 16 + lr;
    int gb = colp * 512 + kk * 64 + (lg << 4);
    bf16x8 a3h = *(const bf16x8*)(o3h + gb);
    bf16x8 a3l = *(const bf16x8*)(o3l + gb);
#pragma unroll
    for (int nfi = 0; nfi < 2; ++nfi) {
      int row = nfi * 16 + lr;
      int off = (row * 512 + kk * 64 + (lg << 4)) ^ ((row & 7) << 4);
      bf16x8 b3h = *(const bf16x8*)(h2hi + off);
      bf16x8 b3l = *(const bf16x8*)(h2lo + off);
      acc3[nfi] = MFMA16(a3h, b3h, acc3[nfi]);
      acc3[nfi] = MFMA16(a3h, b3l, acc3[nfi]);
      acc3[nfi] = MFMA16(a3l, b3h, acc3[nfi]);
    }
  }
#pragma unroll
  for (int nfi = 0; nfi < 2; ++nfi) {
    int row = nfi * 16 + lr;
    int col0 = w * 16 + (lg << 2);
    f32x4 bv = *(const f32x4*)(bo3 + col0);
    f32x4 iv = *(const f32x4*)(inputs + (r0 + row) * 64 + col0);
    f32x4 o;
#pragma unroll
    for (int i2 = 0; i2 < 4; ++i2) o[i2] = acc3[nfi][i2] + bv[i2] + iv[i2];
    *(f32x4*)(out + (r0 + row) * 64 + col0) = o;
  }
}

// ===========================================================================
extern "C" void kernel_launch(void* const* d_in, const int* in_sizes, int n_in,
                              void* d_out, int out_size, void* d_ws, size_t ws_size,
                              hipStream_t stream) {
  (void)in_sizes; (void)n_in; (void)out_size;
  if (ws_size < (size_t)WS_NEED) return;  // need 2 MB scratch

  const float* inputs   = (const float*)d_in[0];
  const float* rel_type = (const float*)d_in[1];
  const float* W1  = (const float*)d_in[4];
  const float* b1  = (const float*)d_in[5];
  const float* W2  = (const float*)d_in[6];
  const float* b2  = (const float*)d_in[7];
  const float* Wo1 = (const float*)d_in[8];
  const float* bo1 = (const float*)d_in[9];
  const float* Wo2 = (const float*)d_in[10];
  const float* bo2 = (const float*)d_in[11];
  const float* Wo3 = (const float*)d_in[12];
  const float* bo3 = (const float*)d_in[13];

  char* ws = (char*)d_ws;
  float* agg  = (float*)(ws + WS_AGG);
  float* out  = (float*)d_out;

  k0_convert<<<dim3(1216), dim3(256), 0, stream>>>(W1, W2, Wo1, Wo2, Wo3, ws);
  k1_edge<<<dim3(4096), dim3(256), 0, stream>>>(inputs, rel_type, b1, b2, ws, agg);
  k3_node<<<dim3(128), dim3(256), 0, stream>>>(inputs, agg, ws, bo1, bo2, bo3, out);
}